// Round 16
// baseline (239.376 us; speedup 1.0000x reference)
//
#include <hip/hip_runtime.h>
#include <stdint.h>

// GIN layer, f32 interface. bf16 MFMA GEMMs with BN-stat epilogues.
// R16 = R15 (16-node buckets: agg_gemm 48.6->42.6us) with k_bin's
// regression reverted: NBK 64->32 blocks (EPB=25000, NW=25 register
// staging) restores the (block,bucket) atomic count to ~100k (R15's
// NB-doubling raised it to ~196k = +4-5us by the R8 atomic-service
// model). agg_gemm floor = LLC random-line service on the 205MB gather
// (FETCH pinned ~78.5MB); occupancy knobs exhausted (R15: 56% at both
// 4- and 8-block/CU caps).

#define NN 50000
#define NE 800000
#define DD 128
#define BN_EPS 1e-5f
#define NB 3125    // 50000/16 buckets (16 dst nodes each, exact)
#define CAPB 448   // bucket region capacity: mean 256 + 12 sigma
#define NBK 32     // binning blocks
#define EPB 25000  // edges per binning block (32*25000 = 800000)
#define HS 68      // hrow LDS stride in uints (16B-aligned, bank-safe)

typedef short bf16x8 __attribute__((ext_vector_type(8)));
typedef float f32x4 __attribute__((ext_vector_type(4)));

__device__ __forceinline__ float bf2f(unsigned short u) {
    return __uint_as_float(((unsigned int)u) << 16);
}
__device__ __forceinline__ unsigned short f2bf(float f) {
    unsigned int u = __float_as_uint(f);
    u += 0x7fffu + ((u >> 16) & 1u);  // RNE
    return (unsigned short)(u >> 16);
}
__device__ __forceinline__ float plo(unsigned int p) { return bf2f((unsigned short)(p & 0xffffu)); }
__device__ __forceinline__ float phi(unsigned int p) { return bf2f((unsigned short)(p >> 16)); }

// ---- feats f32 -> bf16 packed; W transposes; cursor init (one launch) ----
__global__ __launch_bounds__(256) void k_prep(
    const float* __restrict__ feats, unsigned int* __restrict__ fb,
    const float* __restrict__ W1, const float* __restrict__ W2,
    unsigned short* __restrict__ Wt1, unsigned short* __restrict__ Wt2,
    unsigned int* __restrict__ bcur)
{
    int g = blockIdx.x * 256 + threadIdx.x;   // 1.6M threads, 4 floats each
    float4 v = *reinterpret_cast<const float4*>(feats + (size_t)g * 4);
    uint2 o;
    o.x = (unsigned int)f2bf(v.x) | ((unsigned int)f2bf(v.y) << 16);
    o.y = (unsigned int)f2bf(v.z) | ((unsigned int)f2bf(v.w) << 16);
    *reinterpret_cast<uint2*>(fb + (size_t)g * 2) = o;
    if (g < 16384) {
        int row = g >> 7, col = g & 127;
        Wt1[col * DD + row] = f2bf(W1[g]);
    } else if (g < 32768) {
        int h = g - 16384;
        int row = h >> 7, col = h & 127;
        Wt2[col * DD + row] = f2bf(W2[h]);
    }
    if (g < NB) bcur[(size_t)g * 16] = (unsigned int)g * CAPB;
}

// ---- edge binning: register-staged counting sort, 1 atomic/(block,bucket) --
// word = src<<16 | dst (both < 65536). bucket = dst>>4. 32 blocks x 1024 thr.
#define NW 25
__global__ __launch_bounds__(1024) void k_bin(
    const int* __restrict__ src, const int* __restrict__ dst,
    unsigned int* __restrict__ bcur, unsigned int* __restrict__ tmp)
{
    __shared__ unsigned int lhist[NB];
    __shared__ unsigned int lbase[NB];
    int tid = threadIdx.x;
    int e0 = blockIdx.x * EPB;
    for (int c = tid; c < NB; c += 1024) lhist[c] = 0u;
    __syncthreads();
    unsigned int wreg[NW];
    unsigned short lo[NW];
#pragma unroll
    for (int k = 0; k < NW; ++k) {
        int i = tid + k * 1024;
        if (i < EPB) {
            int d = dst[e0 + i];
            int s = src[e0 + i];
            wreg[k] = ((unsigned int)s << 16) | (unsigned int)d;
            lo[k] = (unsigned short)atomicAdd(&lhist[d >> 4], 1u);
        }
    }
    __syncthreads();
    for (int c = tid; c < NB; c += 1024) {
        unsigned int cnt = lhist[c];
        lbase[c] = cnt ? atomicAdd(&bcur[(size_t)c * 16], cnt) : 0u;
    }
    __syncthreads();
#pragma unroll
    for (int k = 0; k < NW; ++k) {
        int i = tid + k * 1024;
        if (i < EPB) {
            unsigned int w = wreg[k];
            int b = (int)((w & 0xffffu) >> 4);
            unsigned int pos = lbase[b] + (unsigned int)lo[k];
            if (pos < (unsigned int)(b + 1) * CAPB) tmp[pos] = w;
        }
    }
}

// ---- fused: per-bucket sort by dst -> register max (unroll 8) ->
//      h0 tile in LDS -> 16x128 @ 128x128 bf16 MFMA (Y1 + BN partials) ----
// grid = NB, 256 threads = 4 waves; wave w: 4 dsts in phase 2, 16x32 GEMM
// piece in phase 3. 50000%16==0 -> no row bounds checks anywhere.
__global__ __launch_bounds__(256) void k_agg_gemm(
    const unsigned int* __restrict__ F,   // fb as uint rows of 64
    const unsigned int* __restrict__ tmp,
    const unsigned int* __restrict__ bcur,
    const unsigned short* __restrict__ Wt, const float* __restrict__ bias,
    unsigned short* __restrict__ Y, float* __restrict__ partials)
{
    __shared__ unsigned int sorted[CAPB];
    __shared__ unsigned int hist[16];
    __shared__ unsigned int hbase[17];
    __shared__ unsigned int hrow[16 * HS];   // packed bf16 h0 tile
    int tid = threadIdx.x;
    int b = blockIdx.x;
    if (tid < 16) hist[tid] = 0u;
    __syncthreads();
    unsigned int rb = (unsigned int)b * CAPB;
    unsigned int cnt = bcur[(size_t)b * 16] - rb;
    if (cnt > CAPB) cnt = CAPB;

    // phase 1: load words (coalesced), LDS hist by dst&15 (each thr <=2)
    unsigned int wreg[2]; unsigned short lo[2]; int nw = 0;
    for (unsigned int i = tid; i < cnt; i += 256) {
        unsigned int ww = tmp[rb + i];
        wreg[nw] = ww;
        lo[nw] = (unsigned short)atomicAdd(&hist[ww & 15], 1u);
        nw++;
    }
    __syncthreads();
    if (tid == 0) {
        unsigned int acc = 0;
#pragma unroll
        for (int i = 0; i < 16; ++i) { hbase[i] = acc; acc += hist[i]; }
        hbase[16] = acc;
    }
    __syncthreads();
    for (int k = 0; k < nw; ++k)
        sorted[hbase[wreg[k] & 15] + (unsigned int)lo[k]] = wreg[k];
    __syncthreads();

    // phase 2: wave per 4 dsts; register max over run (unroll 8)
    int wave = tid >> 6, lane = tid & 63;
    int n0 = b * 16;
#pragma unroll 1
    for (int dd = wave * 4; dd < wave * 4 + 4; ++dd) {
        int n = n0 + dd;
        unsigned int pfself = F[n * 64 + lane];   // hoisted, independent
        int st = (int)hbase[dd], en = (int)hbase[dd + 1];
        float m0 = -3.0e38f, m1 = -3.0e38f;
        int i = st;
        for (; i + 8 <= en; i += 8) {
            unsigned int w0 = sorted[i],     w1 = sorted[i + 1];
            unsigned int w2 = sorted[i + 2], w3 = sorted[i + 3];
            unsigned int w4 = sorted[i + 4], w5 = sorted[i + 5];
            unsigned int w6 = sorted[i + 6], w7 = sorted[i + 7];
            unsigned int u0 = F[(w0 >> 16) * 64 + lane];
            unsigned int u1 = F[(w1 >> 16) * 64 + lane];
            unsigned int u2 = F[(w2 >> 16) * 64 + lane];
            unsigned int u3 = F[(w3 >> 16) * 64 + lane];
            unsigned int u4 = F[(w4 >> 16) * 64 + lane];
            unsigned int u5 = F[(w5 >> 16) * 64 + lane];
            unsigned int u6 = F[(w6 >> 16) * 64 + lane];
            unsigned int u7 = F[(w7 >> 16) * 64 + lane];
            float a0 = fmaxf(plo(u0), plo(u1)), a1 = fmaxf(plo(u2), plo(u3));
            float a2 = fmaxf(plo(u4), plo(u5)), a3 = fmaxf(plo(u6), plo(u7));
            float b0 = fmaxf(phi(u0), phi(u1)), b1 = fmaxf(phi(u2), phi(u3));
            float b2 = fmaxf(phi(u4), phi(u5)), b3 = fmaxf(phi(u6), phi(u7));
            m0 = fmaxf(m0, fmaxf(fmaxf(a0, a1), fmaxf(a2, a3)));
            m1 = fmaxf(m1, fmaxf(fmaxf(b0, b1), fmaxf(b2, b3)));
        }
        for (; i + 4 <= en; i += 4) {
            unsigned int w0 = sorted[i],     w1 = sorted[i + 1];
            unsigned int w2 = sorted[i + 2], w3 = sorted[i + 3];
            unsigned int u0 = F[(w0 >> 16) * 64 + lane];
            unsigned int u1 = F[(w1 >> 16) * 64 + lane];
            unsigned int u2 = F[(w2 >> 16) * 64 + lane];
            unsigned int u3 = F[(w3 >> 16) * 64 + lane];
            m0 = fmaxf(m0, fmaxf(fmaxf(plo(u0), plo(u1)), fmaxf(plo(u2), plo(u3))));
            m1 = fmaxf(m1, fmaxf(fmaxf(phi(u0), phi(u1)), fmaxf(phi(u2), phi(u3))));
        }
        for (; i < en; ++i) {
            unsigned int ww = sorted[i];
            unsigned int u = F[(ww >> 16) * 64 + lane];
            m0 = fmaxf(m0, plo(u));
            m1 = fmaxf(m1, phi(u));
        }
        if (en == st) { m0 = 0.f; m1 = 0.f; }  // no in-edges -> agg = 0
        hrow[dd * HS + lane] = (unsigned int)f2bf(plo(pfself) + m0) |
                               ((unsigned int)f2bf(phi(pfself) + m1) << 16);
    }
    __syncthreads();

    // phase 3: 16x128 GEMM; wave w = 16 rows x cols [w*32, w*32+32).
    int quad = lane >> 4, l16 = lane & 15;
    int nh = wave * 32;
    int kq = quad * 8;
    f32x4 acc[2];
#pragma unroll
    for (int j = 0; j < 2; ++j)
#pragma unroll
        for (int r = 0; r < 4; ++r) acc[j][r] = 0.f;
#pragma unroll
    for (int k0 = 0; k0 < 128; k0 += 32) {
        bf16x8 a = *reinterpret_cast<const bf16x8*>(&hrow[l16 * HS + ((k0 + kq) >> 1)]);
#pragma unroll
        for (int j = 0; j < 2; ++j) {
            bf16x8 bb = *reinterpret_cast<const bf16x8*>(Wt + (nh + j * 16 + l16) * DD + k0 + kq);
            acc[j] = __builtin_amdgcn_mfma_f32_16x16x32_bf16(a, bb, acc[j], 0, 0, 0);
        }
    }

    // epilogue: each col owned by exactly one wave -> direct partials store
    int rbase = n0 + quad * 4;
#pragma unroll
    for (int j = 0; j < 2; ++j) {
        int col = nh + j * 16 + l16;
        float bcol = bias[col];
        float s = 0.f, q = 0.f;
#pragma unroll
        for (int r = 0; r < 4; ++r) {
            float v = acc[j][r] + bcol;
            Y[(rbase + r) * DD + col] = f2bf(v);
            s += v;
            q += v * v;
        }
        s += __shfl_xor(s, 16, 64);
        s += __shfl_xor(s, 32, 64);
        q += __shfl_xor(q, 16, 64);
        q += __shfl_xor(q, 32, 64);
        if (quad == 0) {
            partials[b * 256 + col] = s;
            partials[b * 256 + 128 + col] = q;
        }
    }
}

// ---- GEMM2: Y2 = relu(a1*Y1+c1) @ W2 + b2 (bf16 MFMA) + col sum/sumsq ----
// grid 782, block 512 = 8 waves; block covers 64 rows; wave = 16r x 64c.
__global__ __launch_bounds__(512) void k_gemm2(
    const unsigned short* __restrict__ X, const unsigned short* __restrict__ Wt,
    const float* __restrict__ bias, const float* __restrict__ pa,
    const float* __restrict__ pc, unsigned short* __restrict__ Y,
    float* __restrict__ partials)
{
    __shared__ float lsum[128], lsq[128];
    int tid = threadIdx.x;
    if (tid < 128) { lsum[tid] = 0.f; lsq[tid] = 0.f; }
    __syncthreads();
    int wave = tid >> 6, lane = tid & 63;
    int quad = lane >> 4, l16 = lane & 15;
    int m0 = blockIdx.x * 64 + (wave >> 1) * 16;
    int nh = (wave & 1) * 64;
    int myrow = m0 + l16;
    int kq = quad * 8;

    f32x4 acc[4];
#pragma unroll
    for (int j = 0; j < 4; ++j)
#pragma unroll
        for (int r = 0; r < 4; ++r) acc[j][r] = 0.f;

#pragma unroll
    for (int k0 = 0; k0 < 128; k0 += 32) {
        bf16x8 a;
        if (myrow < NN) {
            a = *reinterpret_cast<const bf16x8*>(X + myrow * DD + k0 + kq);
            float4 av0 = *reinterpret_cast<const float4*>(pa + k0 + kq);
            float4 av1 = *reinterpret_cast<const float4*>(pa + k0 + kq + 4);
            float4 cv0 = *reinterpret_cast<const float4*>(pc + k0 + kq);
            float4 cv1 = *reinterpret_cast<const float4*>(pc + k0 + kq + 4);
            float fa[8] = {av0.x, av0.y, av0.z, av0.w, av1.x, av1.y, av1.z, av1.w};
            float fc[8] = {cv0.x, cv0.y, cv0.z, cv0.w, cv1.x, cv1.y, cv1.z, cv1.w};
#pragma unroll
            for (int j = 0; j < 8; ++j) {
                float v = fmaxf(fa[j] * bf2f((unsigned short)a[j]) + fc[j], 0.f);
                a[j] = (short)f2bf(v);
            }
        } else {
#pragma unroll
            for (int j = 0; j < 8; ++j) a[j] = 0;
        }
#pragma unroll
        for (int j = 0; j < 4; ++j) {
            bf16x8 bb = *reinterpret_cast<const bf16x8*>(Wt + (nh + j * 16 + l16) * DD + k0 + kq);
            acc[j] = __builtin_amdgcn_mfma_f32_16x16x32_bf16(a, bb, acc[j], 0, 0, 0);
        }
    }

    int rbase = m0 + quad * 4;
#pragma unroll
    for (int j = 0; j < 4; ++j) {
        int col = nh + j * 16 + l16;
        float bcol = bias[col];
        float s = 0.f, q = 0.f;
#pragma unroll
        for (int r = 0; r < 4; ++r) {
            int row = rbase + r;
            if (row < NN) {
                float v = acc[j][r] + bcol;
                Y[row * DD + col] = f2bf(v);
                s += v;
                q += v * v;
            }
        }
        s += __shfl_xor(s, 16, 64);
        s += __shfl_xor(s, 32, 64);
        q += __shfl_xor(q, 16, 64);
        q += __shfl_xor(q, 32, 64);
        if (quad == 0) {
            atomicAdd(&lsum[col], s);
            atomicAdd(&lsq[col], q);
        }
    }
    __syncthreads();
    if (tid < 128) {
        partials[blockIdx.x * 256 + tid] = lsum[tid];
        partials[blockIdx.x * 256 + 128 + tid] = lsq[tid];
    }
}

// ---- reduce partials + BN affine: a = g*rsqrt(var+eps), c = be - mean*a ----
__global__ void k_redparams(const float* __restrict__ partials, int nblk,
                            const float* __restrict__ g, const float* __restrict__ be,
                            float* __restrict__ a, float* __restrict__ c) {
    __shared__ float ls[256], lq[256];
    int t = threadIdx.x;
    int col = blockIdx.x;  // 0..127
    float s = 0.f, q = 0.f;
    for (int i = t; i < nblk; i += 256) {
        s += partials[i * 256 + col];
        q += partials[i * 256 + 128 + col];
    }
    ls[t] = s; lq[t] = q;
    __syncthreads();
    for (int off = 128; off > 0; off >>= 1) {
        if (t < off) { ls[t] += ls[t + off]; lq[t] += lq[t + off]; }
        __syncthreads();
    }
    if (t == 0) {
        float mean = ls[0] / (float)NN;
        float var = fmaxf(lq[0] / (float)NN - mean * mean, 0.f);
        float av = g[col] * rsqrtf(var + BN_EPS);
        a[col] = av;
        c[col] = be[col] - mean * av;
    }
}

// ---- stats of z = relu(a2*Y2 + c2), vectorized (2 cols/thread) ----
__global__ __launch_bounds__(256) void k_zstats(
    const unsigned int* __restrict__ Y2u, const float* __restrict__ a2,
    const float* __restrict__ c2, float* __restrict__ partials)
{
    __shared__ float ls[256], lq[256];
    int t = threadIdx.x;
    int cp = t & 63;           // uint col index (covers cols 2cp, 2cp+1)
    int r4 = t >> 6;           // 0..3
    int col0 = cp * 2;
    float av0 = a2[col0],     cv0 = c2[col0];
    float av1 = a2[col0 + 1], cv1 = c2[col0 + 1];
    float s0 = 0.f, q0 = 0.f, s1 = 0.f, q1 = 0.f;
    for (int row = blockIdx.x * 4 + r4; row < NN; row += gridDim.x * 4) {
        unsigned int p = Y2u[row * 64 + cp];
        float z0 = fmaxf(av0 * plo(p) + cv0, 0.f);
        float z1 = fmaxf(av1 * phi(p) + cv1, 0.f);
        s0 += z0; q0 += z0 * z0;
        s1 += z1; q1 += z1 * z1;
    }
    ls[t] = s0; lq[t] = q0;
    __syncthreads();
    if (t < 64) {
        float S = ls[t] + ls[t + 64] + ls[t + 128] + ls[t + 192];
        float Q = lq[t] + lq[t + 64] + lq[t + 128] + lq[t + 192];
        partials[blockIdx.x * 256 + t * 2] = S;
        partials[blockIdx.x * 256 + 128 + t * 2] = Q;
    }
    __syncthreads();
    ls[t] = s1; lq[t] = q1;
    __syncthreads();
    if (t < 64) {
        float S = ls[t] + ls[t + 64] + ls[t + 128] + ls[t + 192];
        float Q = lq[t] + lq[t + 64] + lq[t + 128] + lq[t + 192];
        partials[blockIdx.x * 256 + t * 2 + 1] = S;
        partials[blockIdx.x * 256 + 128 + t * 2 + 1] = Q;
    }
}

// ---- out = a3*relu(a2*Y2+c2) + c3, f32 out ----
__global__ __launch_bounds__(256) void k_out(
    const unsigned short* __restrict__ Y2, const float* __restrict__ a2,
    const float* __restrict__ c2, const float* __restrict__ a3,
    const float* __restrict__ c3, float* __restrict__ out)
{
    int g = blockIdx.x * 256 + threadIdx.x;
    int base = g * 4;
    int c0 = base & 127;
    uint2 p = *reinterpret_cast<const uint2*>(Y2 + base);
    float4 av2 = *reinterpret_cast<const float4*>(a2 + c0);
    float4 cv2 = *reinterpret_cast<const float4*>(c2 + c0);
    float4 av3 = *reinterpret_cast<const float4*>(a3 + c0);
    float4 cv3 = *reinterpret_cast<const float4*>(c3 + c0);
    float z0 = fmaxf(av2.x * plo(p.x) + cv2.x, 0.f);
    float z1 = fmaxf(av2.y * phi(p.x) + cv2.y, 0.f);
    float z2 = fmaxf(av2.z * plo(p.y) + cv2.z, 0.f);
    float z3 = fmaxf(av2.w * phi(p.y) + cv2.w, 0.f);
    float4 o;
    o.x = av3.x * z0 + cv3.x;
    o.y = av3.y * z1 + cv3.y;
    o.z = av3.z * z2 + cv3.z;
    o.w = av3.w * z3 + cv3.w;
    *reinterpret_cast<float4*>(out + base) = o;
}

extern "C" void kernel_launch(void* const* d_in, const int* in_sizes, int n_in,
                              void* d_out, int out_size, void* d_ws, size_t ws_size,
                              hipStream_t stream) {
    (void)in_sizes; (void)n_in; (void)out_size; (void)ws_size;
    const float* feats = (const float*)d_in[0];
    const int* src = (const int*)d_in[1];
    const int* dst = (const int*)d_in[2];
    const float* W1 = (const float*)d_in[3];
    const float* b1 = (const float*)d_in[4];
    const float* g1 = (const float*)d_in[5];
    const float* be1 = (const float*)d_in[6];
    const float* W2 = (const float*)d_in[7];
    const float* b2 = (const float*)d_in[8];
    const float* g2 = (const float*)d_in[9];
    const float* be2 = (const float*)d_in[10];
    const float* g3 = (const float*)d_in[11];
    const float* be3 = (const float*)d_in[12];
    float* out = (float*)d_out;

    char* p = (char*)d_ws;
    auto alloc = [&](size_t n) { char* r = p; p += (n + 255) & ~(size_t)255; return r; };
    unsigned int* fb = (unsigned int*)alloc((size_t)NN * 64 * 4);      // packed bf16
    unsigned int* bcur = (unsigned int*)alloc((size_t)NB * 16 * 4);    // line-padded
    unsigned int* tmp = (unsigned int*)alloc((size_t)NB * CAPB * 4);
    unsigned short* Y1 = (unsigned short*)alloc((size_t)NN * DD * 2);
    unsigned short* Y2 = (unsigned short*)alloc((size_t)NN * DD * 2);
    unsigned short* Wt1 = (unsigned short*)alloc((size_t)DD * DD * 2);
    unsigned short* Wt2 = (unsigned short*)alloc((size_t)DD * DD * 2);
    float* partials = (float*)alloc((size_t)3136 * 256 * 4);
    float* a1 = (float*)alloc(DD * 4); float* c1 = (float*)alloc(DD * 4);
    float* a2 = (float*)alloc(DD * 4); float* c2 = (float*)alloc(DD * 4);
    float* a3 = (float*)alloc(DD * 4); float* c3 = (float*)alloc(DD * 4);

    k_prep<<<6250, 256, 0, stream>>>(feats, fb, W1, W2, Wt1, Wt2, bcur);
    k_bin<<<NBK, 1024, 0, stream>>>(src, dst, bcur, tmp);
    // fused aggregation + layer-1 GEMM
    k_agg_gemm<<<NB, 256, 0, stream>>>(fb, tmp, bcur, Wt1, b1, Y1, partials);
    k_redparams<<<128, 256, 0, stream>>>(partials, NB, g1, be1, a1, c1);
    // layer 2 (BN1+ReLU fused into A-load)
    k_gemm2<<<782, 512, 0, stream>>>(Y1, Wt2, b2, a1, c1, Y2, partials);
    k_redparams<<<128, 256, 0, stream>>>(partials, 782, g2, be2, a2, c2);
    // outer BN over z = relu(a2*Y2+c2)
    k_zstats<<<256, 256, 0, stream>>>((const unsigned int*)Y2, a2, c2, partials);
    k_redparams<<<128, 256, 0, stream>>>(partials, 256, g3, be3, a3, c3);
    k_out<<<6250, 256, 0, stream>>>(Y2, a2, c2, a3, c3, out);
}

// Round 17
// 230.921 us; speedup vs baseline: 1.0366x; 1.0366x over previous
//
#include <hip/hip_runtime.h>
#include <stdint.h>

// GIN layer, f32 interface. bf16 MFMA GEMMs with BN-stat epilogues.
// R17: decouple binning from aggregation granularity. k_bin = R14's best
// shape (64 blocks x dst>>5 coarse buckets = 100k atomic cells, 64-CU
// spread; R16's 32-block variant lost CU parallelism). k_agg_gemm keeps
// the 16-node quantum (R15: -6us) via TWO blocks per coarse bucket:
// each sorts the shared region by dst&31 (duplicated, LDS-cheap) and
// processes only its half's 16 dsts. agg_gemm floor = LLC random-line
// service on the 205MB gather (FETCH pinned ~78.5MB, R13-R16).

#define NN 50000
#define NE 800000
#define DD 128
#define BN_EPS 1e-5f
#define NB1 1563   // coarse buckets (32 dst nodes each): binning regions
#define NG 3125    // agg blocks = 2 per coarse bucket (tail: half 0 only)
#define CAPB 768   // coarse region capacity: mean 512 + ~11 sigma
#define NBK 64     // binning blocks
#define EPB 12500  // edges per binning block (64*12500 = 800000)
#define HS 68      // hrow LDS stride in uints (16B-aligned, bank-safe)

typedef short bf16x8 __attribute__((ext_vector_type(8)));
typedef float f32x4 __attribute__((ext_vector_type(4)));

__device__ __forceinline__ float bf2f(unsigned short u) {
    return __uint_as_float(((unsigned int)u) << 16);
}
__device__ __forceinline__ unsigned short f2bf(float f) {
    unsigned int u = __float_as_uint(f);
    u += 0x7fffu + ((u >> 16) & 1u);  // RNE
    return (unsigned short)(u >> 16);
}
__device__ __forceinline__ float plo(unsigned int p) { return bf2f((unsigned short)(p & 0xffffu)); }
__device__ __forceinline__ float phi(unsigned int p) { return bf2f((unsigned short)(p >> 16)); }

// ---- feats f32 -> bf16 packed; W transposes; cursor init (one launch) ----
__global__ __launch_bounds__(256) void k_prep(
    const float* __restrict__ feats, unsigned int* __restrict__ fb,
    const float* __restrict__ W1, const float* __restrict__ W2,
    unsigned short* __restrict__ Wt1, unsigned short* __restrict__ Wt2,
    unsigned int* __restrict__ bcur)
{
    int g = blockIdx.x * 256 + threadIdx.x;   // 1.6M threads, 4 floats each
    float4 v = *reinterpret_cast<const float4*>(feats + (size_t)g * 4);
    uint2 o;
    o.x = (unsigned int)f2bf(v.x) | ((unsigned int)f2bf(v.y) << 16);
    o.y = (unsigned int)f2bf(v.z) | ((unsigned int)f2bf(v.w) << 16);
    *reinterpret_cast<uint2*>(fb + (size_t)g * 2) = o;
    if (g < 16384) {
        int row = g >> 7, col = g & 127;
        Wt1[col * DD + row] = f2bf(W1[g]);
    } else if (g < 32768) {
        int h = g - 16384;
        int row = h >> 7, col = h & 127;
        Wt2[col * DD + row] = f2bf(W2[h]);
    }
    if (g < NB1) bcur[(size_t)g * 16] = (unsigned int)g * CAPB;
}

// ---- edge binning: register-staged counting sort, 1 atomic/(block,bucket) --
// word = src<<16 | dst (both < 65536). bucket = dst>>5. 64 blocks x 1024 thr.
#define NW 13
__global__ __launch_bounds__(1024) void k_bin(
    const int* __restrict__ src, const int* __restrict__ dst,
    unsigned int* __restrict__ bcur, unsigned int* __restrict__ tmp)
{
    __shared__ unsigned int lhist[NB1];
    __shared__ unsigned int lbase[NB1];
    int tid = threadIdx.x;
    int e0 = blockIdx.x * EPB;
    for (int c = tid; c < NB1; c += 1024) lhist[c] = 0u;
    __syncthreads();
    unsigned int wreg[NW];
    unsigned short lo[NW];
#pragma unroll
    for (int k = 0; k < NW; ++k) {
        int i = tid + k * 1024;
        if (i < EPB) {
            int d = dst[e0 + i];
            int s = src[e0 + i];
            wreg[k] = ((unsigned int)s << 16) | (unsigned int)d;
            lo[k] = (unsigned short)atomicAdd(&lhist[d >> 5], 1u);
        }
    }
    __syncthreads();
    for (int c = tid; c < NB1; c += 1024) {
        unsigned int cnt = lhist[c];
        lbase[c] = cnt ? atomicAdd(&bcur[(size_t)c * 16], cnt) : 0u;
    }
    __syncthreads();
#pragma unroll
    for (int k = 0; k < NW; ++k) {
        int i = tid + k * 1024;
        if (i < EPB) {
            unsigned int w = wreg[k];
            int b = (int)((w & 0xffffu) >> 5);
            unsigned int pos = lbase[b] + (unsigned int)lo[k];
            if (pos < (unsigned int)(b + 1) * CAPB) tmp[pos] = w;
        }
    }
}

// ---- fused: 2 blocks per coarse bucket; each sorts the shared region by
//      dst&31, then register-max + 16x128 MFMA over ITS 16 dsts ----
// grid = NG (3125), 256 threads = 4 waves. Tail bucket 1562: half 0 only.
__global__ __launch_bounds__(256) void k_agg_gemm(
    const unsigned int* __restrict__ F,   // fb as uint rows of 64
    const unsigned int* __restrict__ tmp,
    const unsigned int* __restrict__ bcur,
    const unsigned short* __restrict__ Wt, const float* __restrict__ bias,
    unsigned short* __restrict__ Y, float* __restrict__ partials)
{
    __shared__ unsigned int sorted[CAPB];
    __shared__ unsigned int hist[32];
    __shared__ unsigned int hbase[33];
    __shared__ unsigned int hrow[16 * HS];   // packed bf16 h0 tile (16 rows)
    int tid = threadIdx.x;
    int bb = blockIdx.x;
    int b = bb >> 1, half = bb & 1;
    if (tid < 32) hist[tid] = 0u;
    __syncthreads();
    unsigned int rb = (unsigned int)b * CAPB;
    unsigned int cnt = bcur[(size_t)b * 16] - rb;
    if (cnt > CAPB) cnt = CAPB;

    // phase 1: load words (coalesced, <=3/thread), LDS hist by dst&31
    unsigned int wreg[3]; unsigned short lo[3]; int nw = 0;
    for (unsigned int i = tid; i < cnt; i += 256) {
        unsigned int ww = tmp[rb + i];
        wreg[nw] = ww;
        lo[nw] = (unsigned short)atomicAdd(&hist[ww & 31], 1u);
        nw++;
    }
    __syncthreads();
    if (tid == 0) {
        unsigned int acc = 0;
#pragma unroll
        for (int i = 0; i < 32; ++i) { hbase[i] = acc; acc += hist[i]; }
        hbase[32] = acc;
    }
    __syncthreads();
    for (int k = 0; k < nw; ++k)
        sorted[hbase[wreg[k] & 31] + (unsigned int)lo[k]] = wreg[k];
    __syncthreads();

    // phase 2: wave per 4 of this half's 16 dsts; register max (unroll 8)
    int wave = tid >> 6, lane = tid & 63;
    int nbase = b * 32 + half * 16;
#pragma unroll 1
    for (int ld = wave * 4; ld < wave * 4 + 4; ++ld) {
        int bin = half * 16 + ld;
        int n = nbase + ld;
        unsigned int pfself = F[n * 64 + lane];   // hoisted, independent
        int st = (int)hbase[bin], en = (int)hbase[bin + 1];
        float m0 = -3.0e38f, m1 = -3.0e38f;
        int i = st;
        for (; i + 8 <= en; i += 8) {
            unsigned int w0 = sorted[i],     w1 = sorted[i + 1];
            unsigned int w2 = sorted[i + 2], w3 = sorted[i + 3];
            unsigned int w4 = sorted[i + 4], w5 = sorted[i + 5];
            unsigned int w6 = sorted[i + 6], w7 = sorted[i + 7];
            unsigned int u0 = F[(w0 >> 16) * 64 + lane];
            unsigned int u1 = F[(w1 >> 16) * 64 + lane];
            unsigned int u2 = F[(w2 >> 16) * 64 + lane];
            unsigned int u3 = F[(w3 >> 16) * 64 + lane];
            unsigned int u4 = F[(w4 >> 16) * 64 + lane];
            unsigned int u5 = F[(w5 >> 16) * 64 + lane];
            unsigned int u6 = F[(w6 >> 16) * 64 + lane];
            unsigned int u7 = F[(w7 >> 16) * 64 + lane];
            float a0 = fmaxf(plo(u0), plo(u1)), a1 = fmaxf(plo(u2), plo(u3));
            float a2 = fmaxf(plo(u4), plo(u5)), a3 = fmaxf(plo(u6), plo(u7));
            float b0 = fmaxf(phi(u0), phi(u1)), b1 = fmaxf(phi(u2), phi(u3));
            float b2 = fmaxf(phi(u4), phi(u5)), b3 = fmaxf(phi(u6), phi(u7));
            m0 = fmaxf(m0, fmaxf(fmaxf(a0, a1), fmaxf(a2, a3)));
            m1 = fmaxf(m1, fmaxf(fmaxf(b0, b1), fmaxf(b2, b3)));
        }
        for (; i + 4 <= en; i += 4) {
            unsigned int w0 = sorted[i],     w1 = sorted[i + 1];
            unsigned int w2 = sorted[i + 2], w3 = sorted[i + 3];
            unsigned int u0 = F[(w0 >> 16) * 64 + lane];
            unsigned int u1 = F[(w1 >> 16) * 64 + lane];
            unsigned int u2 = F[(w2 >> 16) * 64 + lane];
            unsigned int u3 = F[(w3 >> 16) * 64 + lane];
            m0 = fmaxf(m0, fmaxf(fmaxf(plo(u0), plo(u1)), fmaxf(plo(u2), plo(u3))));
            m1 = fmaxf(m1, fmaxf(fmaxf(phi(u0), phi(u1)), fmaxf(phi(u2), phi(u3))));
        }
        for (; i < en; ++i) {
            unsigned int ww = sorted[i];
            unsigned int u = F[(ww >> 16) * 64 + lane];
            m0 = fmaxf(m0, plo(u));
            m1 = fmaxf(m1, phi(u));
        }
        if (en == st) { m0 = 0.f; m1 = 0.f; }  // no in-edges -> agg = 0
        hrow[ld * HS + lane] = (unsigned int)f2bf(plo(pfself) + m0) |
                               ((unsigned int)f2bf(phi(pfself) + m1) << 16);
    }
    __syncthreads();

    // phase 3: 16x128 GEMM; wave w = 16 rows x cols [w*32, w*32+32).
    int quad = lane >> 4, l16 = lane & 15;
    int nh = wave * 32;
    int kq = quad * 8;
    f32x4 acc[2];
#pragma unroll
    for (int j = 0; j < 2; ++j)
#pragma unroll
        for (int r = 0; r < 4; ++r) acc[j][r] = 0.f;
#pragma unroll
    for (int k0 = 0; k0 < 128; k0 += 32) {
        bf16x8 a = *reinterpret_cast<const bf16x8*>(&hrow[l16 * HS + ((k0 + kq) >> 1)]);
#pragma unroll
        for (int j = 0; j < 2; ++j) {
            bf16x8 bb2 = *reinterpret_cast<const bf16x8*>(Wt + (nh + j * 16 + l16) * DD + k0 + kq);
            acc[j] = __builtin_amdgcn_mfma_f32_16x16x32_bf16(a, bb2, acc[j], 0, 0, 0);
        }
    }

    // epilogue: each col owned by exactly one wave -> direct partials store
    int rbase = nbase + quad * 4;
#pragma unroll
    for (int j = 0; j < 2; ++j) {
        int col = nh + j * 16 + l16;
        float bcol = bias[col];
        float s = 0.f, q = 0.f;
#pragma unroll
        for (int r = 0; r < 4; ++r) {
            float v = acc[j][r] + bcol;
            Y[(rbase + r) * DD + col] = f2bf(v);
            s += v;
            q += v * v;
        }
        s += __shfl_xor(s, 16, 64);
        s += __shfl_xor(s, 32, 64);
        q += __shfl_xor(q, 16, 64);
        q += __shfl_xor(q, 32, 64);
        if (quad == 0) {
            partials[bb * 256 + col] = s;
            partials[bb * 256 + 128 + col] = q;
        }
    }
}

// ---- GEMM2: Y2 = relu(a1*Y1+c1) @ W2 + b2 (bf16 MFMA) + col sum/sumsq ----
// grid 782, block 512 = 8 waves; block covers 64 rows; wave = 16r x 64c.
__global__ __launch_bounds__(512) void k_gemm2(
    const unsigned short* __restrict__ X, const unsigned short* __restrict__ Wt,
    const float* __restrict__ bias, const float* __restrict__ pa,
    const float* __restrict__ pc, unsigned short* __restrict__ Y,
    float* __restrict__ partials)
{
    __shared__ float lsum[128], lsq[128];
    int tid = threadIdx.x;
    if (tid < 128) { lsum[tid] = 0.f; lsq[tid] = 0.f; }
    __syncthreads();
    int wave = tid >> 6, lane = tid & 63;
    int quad = lane >> 4, l16 = lane & 15;
    int m0 = blockIdx.x * 64 + (wave >> 1) * 16;
    int nh = (wave & 1) * 64;
    int myrow = m0 + l16;
    int kq = quad * 8;

    f32x4 acc[4];
#pragma unroll
    for (int j = 0; j < 4; ++j)
#pragma unroll
        for (int r = 0; r < 4; ++r) acc[j][r] = 0.f;

#pragma unroll
    for (int k0 = 0; k0 < 128; k0 += 32) {
        bf16x8 a;
        if (myrow < NN) {
            a = *reinterpret_cast<const bf16x8*>(X + myrow * DD + k0 + kq);
            float4 av0 = *reinterpret_cast<const float4*>(pa + k0 + kq);
            float4 av1 = *reinterpret_cast<const float4*>(pa + k0 + kq + 4);
            float4 cv0 = *reinterpret_cast<const float4*>(pc + k0 + kq);
            float4 cv1 = *reinterpret_cast<const float4*>(pc + k0 + kq + 4);
            float fa[8] = {av0.x, av0.y, av0.z, av0.w, av1.x, av1.y, av1.z, av1.w};
            float fc[8] = {cv0.x, cv0.y, cv0.z, cv0.w, cv1.x, cv1.y, cv1.z, cv1.w};
#pragma unroll
            for (int j = 0; j < 8; ++j) {
                float v = fmaxf(fa[j] * bf2f((unsigned short)a[j]) + fc[j], 0.f);
                a[j] = (short)f2bf(v);
            }
        } else {
#pragma unroll
            for (int j = 0; j < 8; ++j) a[j] = 0;
        }
#pragma unroll
        for (int j = 0; j < 4; ++j) {
            bf16x8 bb = *reinterpret_cast<const bf16x8*>(Wt + (nh + j * 16 + l16) * DD + k0 + kq);
            acc[j] = __builtin_amdgcn_mfma_f32_16x16x32_bf16(a, bb, acc[j], 0, 0, 0);
        }
    }

    int rbase = m0 + quad * 4;
#pragma unroll
    for (int j = 0; j < 4; ++j) {
        int col = nh + j * 16 + l16;
        float bcol = bias[col];
        float s = 0.f, q = 0.f;
#pragma unroll
        for (int r = 0; r < 4; ++r) {
            int row = rbase + r;
            if (row < NN) {
                float v = acc[j][r] + bcol;
                Y[row * DD + col] = f2bf(v);
                s += v;
                q += v * v;
            }
        }
        s += __shfl_xor(s, 16, 64);
        s += __shfl_xor(s, 32, 64);
        q += __shfl_xor(q, 16, 64);
        q += __shfl_xor(q, 32, 64);
        if (quad == 0) {
            atomicAdd(&lsum[col], s);
            atomicAdd(&lsq[col], q);
        }
    }
    __syncthreads();
    if (tid < 128) {
        partials[blockIdx.x * 256 + tid] = lsum[tid];
        partials[blockIdx.x * 256 + 128 + tid] = lsq[tid];
    }
}

// ---- reduce partials + BN affine: a = g*rsqrt(var+eps), c = be - mean*a ----
__global__ void k_redparams(const float* __restrict__ partials, int nblk,
                            const float* __restrict__ g, const float* __restrict__ be,
                            float* __restrict__ a, float* __restrict__ c) {
    __shared__ float ls[256], lq[256];
    int t = threadIdx.x;
    int col = blockIdx.x;  // 0..127
    float s = 0.f, q = 0.f;
    for (int i = t; i < nblk; i += 256) {
        s += partials[i * 256 + col];
        q += partials[i * 256 + 128 + col];
    }
    ls[t] = s; lq[t] = q;
    __syncthreads();
    for (int off = 128; off > 0; off >>= 1) {
        if (t < off) { ls[t] += ls[t + off]; lq[t] += lq[t + off]; }
        __syncthreads();
    }
    if (t == 0) {
        float mean = ls[0] / (float)NN;
        float var = fmaxf(lq[0] / (float)NN - mean * mean, 0.f);
        float av = g[col] * rsqrtf(var + BN_EPS);
        a[col] = av;
        c[col] = be[col] - mean * av;
    }
}

// ---- stats of z = relu(a2*Y2 + c2), vectorized (2 cols/thread) ----
__global__ __launch_bounds__(256) void k_zstats(
    const unsigned int* __restrict__ Y2u, const float* __restrict__ a2,
    const float* __restrict__ c2, float* __restrict__ partials)
{
    __shared__ float ls[256], lq[256];
    int t = threadIdx.x;
    int cp = t & 63;           // uint col index (covers cols 2cp, 2cp+1)
    int r4 = t >> 6;           // 0..3
    int col0 = cp * 2;
    float av0 = a2[col0],     cv0 = c2[col0];
    float av1 = a2[col0 + 1], cv1 = c2[col0 + 1];
    float s0 = 0.f, q0 = 0.f, s1 = 0.f, q1 = 0.f;
    for (int row = blockIdx.x * 4 + r4; row < NN; row += gridDim.x * 4) {
        unsigned int p = Y2u[row * 64 + cp];
        float z0 = fmaxf(av0 * plo(p) + cv0, 0.f);
        float z1 = fmaxf(av1 * phi(p) + cv1, 0.f);
        s0 += z0; q0 += z0 * z0;
        s1 += z1; q1 += z1 * z1;
    }
    ls[t] = s0; lq[t] = q0;
    __syncthreads();
    if (t < 64) {
        float S = ls[t] + ls[t + 64] + ls[t + 128] + ls[t + 192];
        float Q = lq[t] + lq[t + 64] + lq[t + 128] + lq[t + 192];
        partials[blockIdx.x * 256 + t * 2] = S;
        partials[blockIdx.x * 256 + 128 + t * 2] = Q;
    }
    __syncthreads();
    ls[t] = s1; lq[t] = q1;
    __syncthreads();
    if (t < 64) {
        float S = ls[t] + ls[t + 64] + ls[t + 128] + ls[t + 192];
        float Q = lq[t] + lq[t + 64] + lq[t + 128] + lq[t + 192];
        partials[blockIdx.x * 256 + t * 2 + 1] = S;
        partials[blockIdx.x * 256 + 128 + t * 2 + 1] = Q;
    }
}

// ---- out = a3*relu(a2*Y2+c2) + c3, f32 out ----
__global__ __launch_bounds__(256) void k_out(
    const unsigned short* __restrict__ Y2, const float* __restrict__ a2,
    const float* __restrict__ c2, const float* __restrict__ a3,
    const float* __restrict__ c3, float* __restrict__ out)
{
    int g = blockIdx.x * 256 + threadIdx.x;
    int base = g * 4;
    int c0 = base & 127;
    uint2 p = *reinterpret_cast<const uint2*>(Y2 + base);
    float4 av2 = *reinterpret_cast<const float4*>(a2 + c0);
    float4 cv2 = *reinterpret_cast<const float4*>(c2 + c0);
    float4 av3 = *reinterpret_cast<const float4*>(a3 + c0);
    float4 cv3 = *reinterpret_cast<const float4*>(c3 + c0);
    float z0 = fmaxf(av2.x * plo(p.x) + cv2.x, 0.f);
    float z1 = fmaxf(av2.y * phi(p.x) + cv2.y, 0.f);
    float z2 = fmaxf(av2.z * plo(p.y) + cv2.z, 0.f);
    float z3 = fmaxf(av2.w * phi(p.y) + cv2.w, 0.f);
    float4 o;
    o.x = av3.x * z0 + cv3.x;
    o.y = av3.y * z1 + cv3.y;
    o.z = av3.z * z2 + cv3.z;
    o.w = av3.w * z3 + cv3.w;
    *reinterpret_cast<float4*>(out + base) = o;
}

extern "C" void kernel_launch(void* const* d_in, const int* in_sizes, int n_in,
                              void* d_out, int out_size, void* d_ws, size_t ws_size,
                              hipStream_t stream) {
    (void)in_sizes; (void)n_in; (void)out_size; (void)ws_size;
    const float* feats = (const float*)d_in[0];
    const int* src = (const int*)d_in[1];
    const int* dst = (const int*)d_in[2];
    const float* W1 = (const float*)d_in[3];
    const float* b1 = (const float*)d_in[4];
    const float* g1 = (const float*)d_in[5];
    const float* be1 = (const float*)d_in[6];
    const float* W2 = (const float*)d_in[7];
    const float* b2 = (const float*)d_in[8];
    const float* g2 = (const float*)d_in[9];
    const float* be2 = (const float*)d_in[10];
    const float* g3 = (const float*)d_in[11];
    const float* be3 = (const float*)d_in[12];
    float* out = (float*)d_out;

    char* p = (char*)d_ws;
    auto alloc = [&](size_t n) { char* r = p; p += (n + 255) & ~(size_t)255; return r; };
    unsigned int* fb = (unsigned int*)alloc((size_t)NN * 64 * 4);      // packed bf16
    unsigned int* bcur = (unsigned int*)alloc((size_t)NB1 * 16 * 4);   // line-padded
    unsigned int* tmp = (unsigned int*)alloc((size_t)NB1 * CAPB * 4);
    unsigned short* Y1 = (unsigned short*)alloc((size_t)NN * DD * 2);
    unsigned short* Y2 = (unsigned short*)alloc((size_t)NN * DD * 2);
    unsigned short* Wt1 = (unsigned short*)alloc((size_t)DD * DD * 2);
    unsigned short* Wt2 = (unsigned short*)alloc((size_t)DD * DD * 2);
    float* partials = (float*)alloc((size_t)3136 * 256 * 4);
    float* a1 = (float*)alloc(DD * 4); float* c1 = (float*)alloc(DD * 4);
    float* a2 = (float*)alloc(DD * 4); float* c2 = (float*)alloc(DD * 4);
    float* a3 = (float*)alloc(DD * 4); float* c3 = (float*)alloc(DD * 4);

    k_prep<<<6250, 256, 0, stream>>>(feats, fb, W1, W2, Wt1, Wt2, bcur);
    k_bin<<<NBK, 1024, 0, stream>>>(src, dst, bcur, tmp);
    // fused aggregation + layer-1 GEMM (2 blocks per coarse bucket)
    k_agg_gemm<<<NG, 256, 0, stream>>>(fb, tmp, bcur, Wt1, b1, Y1, partials);
    k_redparams<<<128, 256, 0, stream>>>(partials, NG, g1, be1, a1, c1);
    // layer 2 (BN1+ReLU fused into A-load)
    k_gemm2<<<782, 512, 0, stream>>>(Y1, Wt2, b2, a1, c1, Y2, partials);
    k_redparams<<<128, 256, 0, stream>>>(partials, 782, g2, be2, a2, c2);
    // outer BN over z = relu(a2*Y2+c2)
    k_zstats<<<256, 256, 0, stream>>>((const unsigned int*)Y2, a2, c2, partials);
    k_redparams<<<128, 256, 0, stream>>>(partials, 256, g3, be3, a3, c3);
    k_out<<<6250, 256, 0, stream>>>(Y2, a2, c2, a3, c3, out);
}